// Round 3
// baseline (50.423 us; speedup 1.0000x reference)
//
#include <hip/hip_runtime.h>
#include <hip/hip_bf16.h>

#define HH 256
#define WW 256
#define NN 512
#define FXC 300.0f
#define FYC 300.0f
#define CXC 128.0f
#define CYC 128.0f
#define NEARC 0.01f
#define MAXRAD 20.0f

// Per-gaussian packed params (sorted back-to-front in LDS), 12 floats:
// [0]=u [1]=v [2]=x0 [3]=x1 [4]=y0 [5]=y1 [6]=neg_inv_2sig2 [7]=op [8]=r [9]=g [10]=b [11]=pad
#define GP 12

__global__ __launch_bounds__(WW) void fused_kernel(
    const float* __restrict__ pos,      // 512x3
    const float* __restrict__ scl,      // 512x3
    const float* __restrict__ col,      // 512x3
    const float* __restrict__ opac,     // 512
    const float* __restrict__ viewm,    // 16
    const float* __restrict__ bg,       // 3
    float* __restrict__ out)            // 3x256x256
{
    __shared__ float sd[NN];            // depths by original index
    __shared__ float sgp[NN * GP];      // params at sorted rank position
    __shared__ int   slist[NN];         // compacted rank list for this row
    __shared__ int   swave[4];
    __shared__ int   sM;

    const int t = threadIdx.x;
    const int y = blockIdx.x;
    const float yy = (float)y;

    // view matrix rows 0..2 (uniform address -> scalar loads)
    float V[12];
    #pragma unroll
    for (int j = 0; j < 12; ++j) V[j] = viewm[j];

    // ---- Phase 0: project 2 gaussians per thread ----
    const int g0 = t;
    const int g1 = t + WW;

    float cx0, cy0, d0, cx1, cy1, d1;
    {
        const float px = pos[g0 * 3 + 0], py = pos[g0 * 3 + 1], pz = pos[g0 * 3 + 2];
        cx0 = V[0] * px + V[1] * py + V[2]  * pz + V[3];
        cy0 = V[4] * px + V[5] * py + V[6]  * pz + V[7];
        const float cz = V[8] * px + V[9] * py + V[10] * pz + V[11];
        const float zs = cz + 1e-8f;
        const float sgn = (zs > 0.0f) ? 1.0f : ((zs < 0.0f) ? -1.0f : 0.0f);
        d0 = -(fmaxf(fabsf(cz), NEARC) * sgn);
    }
    {
        const float px = pos[g1 * 3 + 0], py = pos[g1 * 3 + 1], pz = pos[g1 * 3 + 2];
        cx1 = V[0] * px + V[1] * py + V[2]  * pz + V[3];
        cy1 = V[4] * px + V[5] * py + V[6]  * pz + V[7];
        const float cz = V[8] * px + V[9] * py + V[10] * pz + V[11];
        const float zs = cz + 1e-8f;
        const float sgn = (zs > 0.0f) ? 1.0f : ((zs < 0.0f) ? -1.0f : 0.0f);
        d1 = -(fmaxf(fabsf(cz), NEARC) * sgn);
    }
    sd[g0] = d0;
    sd[g1] = d1;
    __syncthreads();

    // ---- Phase 1: stable ranks (descending depth, index tie-break) ----
    int r0 = 0, r1 = 0;
    {
        const float4* sd4 = (const float4*)sd;
        #pragma unroll 8
        for (int j4 = 0; j4 < NN / 4; ++j4) {
            const float4 q = sd4[j4];
            const int j = j4 * 4;
            r0 += (q.x > d0) | ((q.x == d0) & (j     < g0));
            r0 += (q.y > d0) | ((q.y == d0) & (j + 1 < g0));
            r0 += (q.z > d0) | ((q.z == d0) & (j + 2 < g0));
            r0 += (q.w > d0) | ((q.w == d0) & (j + 3 < g0));
            r1 += (q.x > d1) | ((q.x == d1) & (j     < g1));
            r1 += (q.y > d1) | ((q.y == d1) & (j + 1 < g1));
            r1 += (q.z > d1) | ((q.z == d1) & (j + 2 < g1));
            r1 += (q.w > d1) | ((q.w == d1) & (j + 3 < g1));
        }
    }

    // ---- Phase 2: compute params, scatter to LDS at rank position ----
    #pragma unroll
    for (int k = 0; k < 2; ++k) {
        const int   g = k ? g1 : g0;
        const int   r = k ? r1 : r0;
        const float d = k ? d1 : d0;
        const float cxx = k ? cx1 : cx0;
        const float cyy = k ? cy1 : cy0;

        float u = 0.0f, v = 0.0f;
        float x0 = 1e9f, x1 = -1e9f, y0 = 1e9f, y1 = -1e9f;
        float neg_inv = 0.0f;
        if (d > 0.0f) {
            u = FXC * cxx / d + CXC;
            v = CYC - FYC * cyy / d;
            const float sm = (scl[g * 3 + 0] + scl[g * 3 + 1] + scl[g * 3 + 2]) * (1.0f / 3.0f);
            float radius = floorf(sm * FXC / d);
            radius = fminf(fmaxf(radius, 1.0f), MAXRAD);
            const float xi = truncf(u);
            const float yi = truncf(v);
            x0 = fmaxf(0.0f, xi - radius);
            x1 = fminf((float)WW, xi + radius + 1.0f);
            y0 = fmaxf(0.0f, yi - radius);
            y1 = fminf((float)HH, yi + radius + 1.0f);
            const float sigma = fmaxf(radius * 0.5f, 1.0f);
            neg_inv = -1.0f / (2.0f * sigma * sigma);
        }
        float* o = &sgp[r * GP];
        o[0]  = u;
        o[1]  = v;
        o[2]  = x0;
        o[3]  = x1;
        o[4]  = y0;
        o[5]  = y1;
        o[6]  = neg_inv;
        o[7]  = opac[g];
        o[8]  = col[g * 3 + 0];
        o[9]  = col[g * 3 + 1];
        o[10] = col[g * 3 + 2];
        o[11] = 0.0f;
    }
    __syncthreads();

    // ---- Phase 3: order-preserving compaction of gaussians touching row y ----
    const int wave = t >> 6;
    const int lane = t & 63;
    const int ia = wave * 128 + lane;
    const int ib = ia + 64;
    const bool fa = (yy >= sgp[ia * GP + 4]) && (yy < sgp[ia * GP + 5]);
    const bool fb = (yy >= sgp[ib * GP + 4]) && (yy < sgp[ib * GP + 5]);
    const unsigned long long ba = __ballot(fa);
    const unsigned long long bb = __ballot(fb);
    const int ca = __popcll(ba);
    if (lane == 0) swave[wave] = ca + __popcll(bb);
    __syncthreads();
    int base = 0;
    #pragma unroll
    for (int w = 0; w < 4; ++w) base += (w < wave) ? swave[w] : 0;
    if (t == 0) sM = swave[0] + swave[1] + swave[2] + swave[3];
    if (fa) slist[base + __popcll(ba & ((1ull << lane) - 1ull))] = ia;
    if (fb) slist[base + ca + __popcll(bb & ((1ull << lane) - 1ull))] = ib;
    __syncthreads();
    const int M = sM;

    // ---- Phase 4: per-pixel ordered blend over M selected gaussians ----
    const float xx = (float)t;
    float cr = bg[0];
    float cg = bg[1];
    float cb = bg[2];

    for (int i = 0; i < M; ++i) {
        const float* p = &sgp[slist[i] * GP];   // slist[i] uniform -> broadcast reads
        float a = 0.0f;
        const float x0 = p[2];
        const float x1 = p[3];
        if (xx >= x0 && xx < x1) {
            const float dx = xx - p[0];
            const float dy = yy - p[1];
            const float ds = dx * dx + dy * dy;
            a = __expf(ds * p[6]) * p[7];
            a = fminf(fmaxf(a, 0.0f), 1.0f);
        }
        const float one_m = 1.0f - a;
        cr = a * p[8]  + one_m * cr;
        cg = a * p[9]  + one_m * cg;
        cb = a * p[10] + one_m * cb;
    }

    const int pix = y * WW + t;
    out[0 * HH * WW + pix] = cr;
    out[1 * HH * WW + pix] = cg;
    out[2 * HH * WW + pix] = cb;
}

extern "C" void kernel_launch(void* const* d_in, const int* in_sizes, int n_in,
                              void* d_out, int out_size, void* d_ws, size_t ws_size,
                              hipStream_t stream) {
    const float* positions  = (const float*)d_in[0];
    const float* scales     = (const float*)d_in[1];
    // d_in[2] = rotations (unused by reference)
    const float* colors     = (const float*)d_in[3];
    const float* opacities  = (const float*)d_in[4];
    const float* view_matrix= (const float*)d_in[5];
    const float* background = (const float*)d_in[6];

    fused_kernel<<<HH, WW, 0, stream>>>(positions, scales, colors, opacities,
                                        view_matrix, background, (float*)d_out);
}

// Round 4
// 15.410 us; speedup vs baseline: 3.2722x; 3.2722x over previous
//
#include <hip/hip_runtime.h>
#include <hip/hip_bf16.h>

#define HH 256
#define WW 256
#define NN 512
#define FXC 300.0f
#define FYC 300.0f
#define CXC 128.0f
#define CYC 128.0f
#define NEARC 0.01f
#define MAXRAD 20.0f

// gp layout: per gaussian (rank-ordered, back-to-front), 3 float4:
//  q0 = {u, v, x0, x1}   q1 = {y0, y1, neg_inv_2sig2, opacity}   q2 = {r, g, b, 0}

#define PREP_BLOCKS 16
#define PREP_GPB    32      // gaussians per prep block

__global__ __launch_bounds__(256) void prep_kernel(
    const float* __restrict__ pos,      // 512x3
    const float* __restrict__ scl,      // 512x3
    const float* __restrict__ col,      // 512x3
    const float* __restrict__ opac,     // 512
    const float* __restrict__ viewm,    // 16
    float* __restrict__ gp)             // 512*12 out (rank-ordered)
{
    __shared__ float sd[NN];
    __shared__ float scx[NN];
    __shared__ float scy[NN];
    __shared__ int   spart[PREP_GPB][9];   // 9: pad -> conflict-free

    const int t = threadIdx.x;
    const int b = blockIdx.x;

    float V[12];
    #pragma unroll
    for (int j = 0; j < 12; ++j) V[j] = viewm[j];

    // ---- Phase A: project all 512 (2 per thread), duplicated per block ----
    #pragma unroll
    for (int k = 0; k < 2; ++k) {
        const int g = t + k * 256;
        const float px = pos[g * 3 + 0], py = pos[g * 3 + 1], pz = pos[g * 3 + 2];
        const float cx = V[0] * px + V[1] * py + V[2]  * pz + V[3];
        const float cy = V[4] * px + V[5] * py + V[6]  * pz + V[7];
        const float cz = V[8] * px + V[9] * py + V[10] * pz + V[11];
        const float zs = cz + 1e-8f;
        const float sgn = (zs > 0.0f) ? 1.0f : ((zs < 0.0f) ? -1.0f : 0.0f);
        const float d = -(fmaxf(fabsf(cz), NEARC) * sgn);
        sd[g]  = d;
        scx[g] = cx;
        scy[g] = cy;
    }
    __syncthreads();

    // ---- Phase B: partial stable ranks. g = b*32+(t&31), chunk c = t>>5 ----
    // wave has only 2 distinct chunk values -> depth reads are LDS broadcasts
    {
        const int gl = t & 31;
        const int c  = t >> 5;
        const int g  = b * PREP_GPB + gl;
        const float dg = sd[g];
        const float4* sd4 = (const float4*)sd;
        int pr = 0;
        #pragma unroll
        for (int k = 0; k < 16; ++k) {
            const int j4 = c * 16 + k;
            const float4 q = sd4[j4];
            const int j = j4 * 4;
            pr += (q.x > dg) | ((q.x == dg) & (j     < g));
            pr += (q.y > dg) | ((q.y == dg) & (j + 1 < g));
            pr += (q.z > dg) | ((q.z == dg) & (j + 2 < g));
            pr += (q.w > dg) | ((q.w == dg) & (j + 3 < g));
        }
        spart[gl][c] = pr;
    }
    __syncthreads();

    // ---- Phase C: 32 threads finalize their gaussian ----
    if (t < PREP_GPB) {
        const int g = b * PREP_GPB + t;
        int r = 0;
        #pragma unroll
        for (int c = 0; c < 8; ++c) r += spart[t][c];

        const float d = sd[g];
        float u = 0.0f, v = 0.0f;
        float x0 = 1e9f, x1 = -1e9f, y0 = 1e9f, y1 = -1e9f;
        float neg_inv = 0.0f;
        if (d > 0.0f) {
            u = FXC * scx[g] / d + CXC;
            v = CYC - FYC * scy[g] / d;
            const float sm = (scl[g * 3 + 0] + scl[g * 3 + 1] + scl[g * 3 + 2]) * (1.0f / 3.0f);
            float radius = floorf(sm * FXC / d);
            radius = fminf(fmaxf(radius, 1.0f), MAXRAD);
            const float xi = truncf(u);
            const float yi = truncf(v);
            x0 = fmaxf(0.0f, xi - radius);
            x1 = fminf((float)WW, xi + radius + 1.0f);
            y0 = fmaxf(0.0f, yi - radius);
            y1 = fminf((float)HH, yi + radius + 1.0f);
            const float sigma = fmaxf(radius * 0.5f, 1.0f);
            neg_inv = -1.0f / (2.0f * sigma * sigma);
        }
        float4* o = (float4*)(gp + r * 12);
        o[0] = make_float4(u, v, x0, x1);
        o[1] = make_float4(y0, y1, neg_inv, opac[g]);
        o[2] = make_float4(col[g * 3 + 0], col[g * 3 + 1], col[g * 3 + 2], 0.0f);
    }
}

__global__ __launch_bounds__(WW) void render_kernel(
    const float* __restrict__ gp,       // 512*12 rank-ordered
    const float* __restrict__ bg,       // 3
    float* __restrict__ out)            // 3x256x256
{
    __shared__ float4 sg[NN * 3];       // 24 KB: all params
    __shared__ int    slist[NN];
    __shared__ int    swave[4];
    __shared__ int    sM;

    const int t = threadIdx.x;
    const int y = blockIdx.x;
    const float yy = (float)y;

    // ---- coalesced full copy: 1536 float4 / 256 threads = 6 each ----
    {
        const float4* src = (const float4*)gp;
        #pragma unroll
        for (int k = 0; k < 6; ++k)
            sg[k * WW + t] = src[k * WW + t];
    }
    __syncthreads();

    // ---- order-preserving compaction of gaussians touching row y ----
    const int wave = t >> 6;
    const int lane = t & 63;
    const int ia = wave * 128 + lane;
    const int ib = ia + 64;
    const float4 qa = sg[ia * 3 + 1];
    const float4 qb = sg[ib * 3 + 1];
    const bool fa = (yy >= qa.x) && (yy < qa.y);
    const bool fb = (yy >= qb.x) && (yy < qb.y);
    const unsigned long long ba = __ballot(fa);
    const unsigned long long bb = __ballot(fb);
    const int ca = __popcll(ba);
    if (lane == 0) swave[wave] = ca + __popcll(bb);
    __syncthreads();
    int base = 0;
    #pragma unroll
    for (int w = 0; w < 4; ++w) base += (w < wave) ? swave[w] : 0;
    if (t == 0) sM = swave[0] + swave[1] + swave[2] + swave[3];
    if (fa) slist[base + __popcll(ba & ((1ull << lane) - 1ull))] = ia;
    if (fb) slist[base + ca + __popcll(bb & ((1ull << lane) - 1ull))] = ib;
    __syncthreads();
    const int M = sM;

    // ---- per-pixel ordered blend over M selected gaussians ----
    const float xx = (float)t;
    float cr = bg[0];
    float cg = bg[1];
    float cb = bg[2];

    for (int i = 0; i < M; ++i) {
        const int gi = slist[i];            // uniform -> broadcast reads
        const float4 q0 = sg[gi * 3 + 0];
        float a = 0.0f;
        if (xx >= q0.z && xx < q0.w) {
            const float4 q1 = sg[gi * 3 + 1];
            const float dx = xx - q0.x;
            const float dy = yy - q0.y;
            a = __expf((dx * dx + dy * dy) * q1.z) * q1.w;
            a = fminf(fmaxf(a, 0.0f), 1.0f);
        }
        const float4 q2 = sg[gi * 3 + 2];
        const float one_m = 1.0f - a;
        cr = a * q2.x + one_m * cr;
        cg = a * q2.y + one_m * cg;
        cb = a * q2.z + one_m * cb;
    }

    const int pix = y * WW + t;
    out[0 * HH * WW + pix] = cr;
    out[1 * HH * WW + pix] = cg;
    out[2 * HH * WW + pix] = cb;
}

extern "C" void kernel_launch(void* const* d_in, const int* in_sizes, int n_in,
                              void* d_out, int out_size, void* d_ws, size_t ws_size,
                              hipStream_t stream) {
    const float* positions  = (const float*)d_in[0];
    const float* scales     = (const float*)d_in[1];
    // d_in[2] = rotations (unused by reference)
    const float* colors     = (const float*)d_in[3];
    const float* opacities  = (const float*)d_in[4];
    const float* view_matrix= (const float*)d_in[5];
    const float* background = (const float*)d_in[6];

    float* gp = (float*)d_ws;               // 512*12 floats = 24 KB

    prep_kernel<<<PREP_BLOCKS, 256, 0, stream>>>(positions, scales, colors,
                                                 opacities, view_matrix, gp);
    render_kernel<<<HH, WW, 0, stream>>>(gp, background, (float*)d_out);
}

// Round 5
// 12.367 us; speedup vs baseline: 4.0771x; 1.2460x over previous
//
#include <hip/hip_runtime.h>
#include <hip/hip_bf16.h>

#define HH 256
#define WW 256
#define NN 512
#define FXC 300.0f
#define FYC 300.0f
#define CXC 128.0f
#define CYC 128.0f
#define NEARC 0.01f
#define MAXRAD 20.0f

// Single fused kernel: one block per image row. Each block independently
// projects all 512 gaussians (O(N) duplicated work -- cheap; the O(N^2)
// global rank-sort from R3 is eliminated entirely), selects the ones
// touching its row, sorts only that short list by (depth desc, idx asc),
// and alpha-blends back-to-front.
//
// LDS per-gaussian params (by ORIGINAL index):
//  sq0 = {u, v, x0, x1}   sq1 = {y0, y1, neg_inv_2sig2, op}   sq2 = {r, g, b, depth}

__global__ __launch_bounds__(WW) void fused_kernel(
    const float* __restrict__ pos,      // 512x3
    const float* __restrict__ scl,      // 512x3
    const float* __restrict__ col,      // 512x3
    const float* __restrict__ opac,     // 512
    const float* __restrict__ viewm,    // 16
    const float* __restrict__ bg,       // 3
    float* __restrict__ out)            // 3x256x256
{
    __shared__ float4 sq0[NN];
    __shared__ float4 sq1[NN];
    __shared__ float4 sq2[NN];
    __shared__ int    slist[NN];        // selected, ascending original index
    __shared__ int    ssort[NN];        // selected, back-to-front order
    __shared__ int    swave[4];
    __shared__ int    sM;

    const int t = threadIdx.x;
    const int y = blockIdx.x;
    const float yy = (float)y;

    float V[12];
    #pragma unroll
    for (int j = 0; j < 12; ++j) V[j] = viewm[j];

    // ---- Phase 0: project + full params for 2 gaussians per thread ----
    #pragma unroll
    for (int k = 0; k < 2; ++k) {
        const int g = t + k * WW;
        const float px = pos[g * 3 + 0], py = pos[g * 3 + 1], pz = pos[g * 3 + 2];
        const float cx = V[0] * px + V[1] * py + V[2]  * pz + V[3];
        const float cy = V[4] * px + V[5] * py + V[6]  * pz + V[7];
        const float cz = V[8] * px + V[9] * py + V[10] * pz + V[11];
        const float zs = cz + 1e-8f;
        const float sgn = (zs > 0.0f) ? 1.0f : ((zs < 0.0f) ? -1.0f : 0.0f);
        const float d = -(fmaxf(fabsf(cz), NEARC) * sgn);

        float u = 0.0f, v = 0.0f;
        float x0 = 1e9f, x1 = -1e9f, y0 = 1e9f, y1 = -1e9f;
        float neg_inv = 0.0f;
        if (d > 0.0f) {
            const float inv_d = 1.0f / d;
            u = FXC * cx * inv_d + CXC;
            v = CYC - FYC * cy * inv_d;
            const float sm = (scl[g * 3 + 0] + scl[g * 3 + 1] + scl[g * 3 + 2]) * (1.0f / 3.0f);
            float radius = floorf(sm * FXC * inv_d);
            radius = fminf(fmaxf(radius, 1.0f), MAXRAD);
            const float xi = truncf(u);
            const float yi = truncf(v);
            x0 = fmaxf(0.0f, xi - radius);
            x1 = fminf((float)WW, xi + radius + 1.0f);
            y0 = fmaxf(0.0f, yi - radius);
            y1 = fminf((float)HH, yi + radius + 1.0f);
            const float sigma = fmaxf(radius * 0.5f, 1.0f);
            neg_inv = -1.0f / (2.0f * sigma * sigma);
        }
        sq0[g] = make_float4(u, v, x0, x1);
        sq1[g] = make_float4(y0, y1, neg_inv, opac[g]);
        sq2[g] = make_float4(col[g * 3 + 0], col[g * 3 + 1], col[g * 3 + 2], d);
    }
    __syncthreads();

    // ---- Phase 1: compact gaussians touching row y (ascending orig index) ----
    const int wave = t >> 6;
    const int lane = t & 63;
    const int ia = wave * 128 + lane;
    const int ib = ia + 64;
    const float4 qa = sq1[ia];
    const float4 qb = sq1[ib];
    const bool fa = (yy >= qa.x) && (yy < qa.y);
    const bool fb = (yy >= qb.x) && (yy < qb.y);
    const unsigned long long ba = __ballot(fa);
    const unsigned long long bb = __ballot(fb);
    const int ca = __popcll(ba);
    if (lane == 0) swave[wave] = ca + __popcll(bb);
    __syncthreads();
    int base = 0;
    #pragma unroll
    for (int w = 0; w < 4; ++w) base += (w < wave) ? swave[w] : 0;
    if (t == 0) sM = swave[0] + swave[1] + swave[2] + swave[3];
    if (fa) slist[base + __popcll(ba & ((1ull << lane) - 1ull))] = ia;
    if (fb) slist[base + ca + __popcll(bb & ((1ull << lane) - 1ull))] = ib;
    __syncthreads();
    const int M = sM;

    // ---- Phase 2: sort the selected list back-to-front ----
    // key: depth desc, original index asc (matches stable argsort(-depths)).
    // M ~ 18 typical: thread i ranks element i with M broadcast LDS reads.
    if (t < M) {
        const int gi = slist[t];
        const float di = sq2[gi].w;
        int r = 0;
        for (int j = 0; j < M; ++j) {
            const int gj = slist[j];
            const float dj = sq2[gj].w;
            r += (dj > di) | ((dj == di) & (gj < gi));
        }
        ssort[r] = gi;
    }
    __syncthreads();

    // ---- Phase 3: per-pixel ordered blend ----
    const float xx = (float)t;
    float cr = bg[0];
    float cg = bg[1];
    float cb = bg[2];

    for (int i = 0; i < M; ++i) {
        const int gi = ssort[i];            // uniform -> broadcast reads
        const float4 q0 = sq0[gi];
        float a = 0.0f;
        if (xx >= q0.z && xx < q0.w) {
            const float4 q1 = sq1[gi];
            const float dx = xx - q0.x;
            const float dy = yy - q0.y;
            a = __expf((dx * dx + dy * dy) * q1.z) * q1.w;
            a = fminf(fmaxf(a, 0.0f), 1.0f);
        }
        const float4 q2 = sq2[gi];
        const float one_m = 1.0f - a;
        cr = a * q2.x + one_m * cr;
        cg = a * q2.y + one_m * cg;
        cb = a * q2.z + one_m * cb;
    }

    const int pix = y * WW + t;
    out[0 * HH * WW + pix] = cr;
    out[1 * HH * WW + pix] = cg;
    out[2 * HH * WW + pix] = cb;
}

extern "C" void kernel_launch(void* const* d_in, const int* in_sizes, int n_in,
                              void* d_out, int out_size, void* d_ws, size_t ws_size,
                              hipStream_t stream) {
    const float* positions  = (const float*)d_in[0];
    const float* scales     = (const float*)d_in[1];
    // d_in[2] = rotations (unused by reference)
    const float* colors     = (const float*)d_in[3];
    const float* opacities  = (const float*)d_in[4];
    const float* view_matrix= (const float*)d_in[5];
    const float* background = (const float*)d_in[6];

    fused_kernel<<<HH, WW, 0, stream>>>(positions, scales, colors, opacities,
                                        view_matrix, background, (float*)d_out);
}

// Round 6
// 12.014 us; speedup vs baseline: 4.1972x; 1.0294x over previous
//
#include <hip/hip_runtime.h>
#include <hip/hip_bf16.h>

#define HH 256
#define WW 256
#define NN 512
#define FXC 300.0f
#define FYC 300.0f
#define CXC 128.0f
#define CYC 128.0f
#define NEARC 0.01f
#define MAXRAD 20.0f

// Single fused kernel: one block (512 threads = 8 waves) per image row.
// Each block projects all 512 gaussians (1/thread), ballot-compacts the
// ones touching its row (M ~ 18), sorts just that list by (depth desc,
// index asc) == stable argsort(-depths), and alpha-blends back-to-front.
//
// LDS per-gaussian params (by ORIGINAL index):
//  sq0 = {u, v, x0, x1}   sq1 = {y0, y1, neg_inv_2sig2, op}   sq2 = {r, g, b, depth}

__global__ __launch_bounds__(2 * WW) void fused_kernel(
    const float* __restrict__ pos,      // 512x3
    const float* __restrict__ scl,      // 512x3
    const float* __restrict__ col,      // 512x3
    const float* __restrict__ opac,     // 512
    const float* __restrict__ viewm,    // 16
    const float* __restrict__ bg,       // 3
    float* __restrict__ out)            // 3x256x256
{
    __shared__ float4 sq0[NN];
    __shared__ float4 sq1[NN];
    __shared__ float4 sq2[NN];
    __shared__ int    slist[NN];        // selected, ascending original index
    __shared__ int    ssort[NN];        // selected, back-to-front order
    __shared__ int    swave[8];
    __shared__ int    sM;

    const int t = threadIdx.x;
    const int y = blockIdx.x;
    const float yy = (float)y;

    // issue background loads early (latency hidden under Phase 0)
    const float bg0 = bg[0];
    const float bg1 = bg[1];
    const float bg2 = bg[2];

    float V[12];
    #pragma unroll
    for (int j = 0; j < 12; ++j) V[j] = viewm[j];

    // ---- Phase 0: project + full params, exactly 1 gaussian per thread ----
    {
        const int g = t;
        const float px = pos[g * 3 + 0], py = pos[g * 3 + 1], pz = pos[g * 3 + 2];
        const float s0 = scl[g * 3 + 0], s1 = scl[g * 3 + 1], s2 = scl[g * 3 + 2];
        const float c0 = col[g * 3 + 0], c1 = col[g * 3 + 1], c2 = col[g * 3 + 2];
        const float op = opac[g];

        const float cx = V[0] * px + V[1] * py + V[2]  * pz + V[3];
        const float cy = V[4] * px + V[5] * py + V[6]  * pz + V[7];
        const float cz = V[8] * px + V[9] * py + V[10] * pz + V[11];
        const float zs = cz + 1e-8f;
        const float sgn = (zs > 0.0f) ? 1.0f : ((zs < 0.0f) ? -1.0f : 0.0f);
        const float d = -(fmaxf(fabsf(cz), NEARC) * sgn);

        float u = 0.0f, v = 0.0f;
        float x0 = 1e9f, x1 = -1e9f, y0 = 1e9f, y1 = -1e9f;
        float neg_inv = 0.0f;
        if (d > 0.0f) {
            const float inv_d = 1.0f / d;
            u = FXC * cx * inv_d + CXC;
            v = CYC - FYC * cy * inv_d;
            const float sm = (s0 + s1 + s2) * (1.0f / 3.0f);
            float radius = floorf(sm * FXC * inv_d);
            radius = fminf(fmaxf(radius, 1.0f), MAXRAD);
            const float xi = truncf(u);
            const float yi = truncf(v);
            x0 = fmaxf(0.0f, xi - radius);
            x1 = fminf((float)WW, xi + radius + 1.0f);
            y0 = fmaxf(0.0f, yi - radius);
            y1 = fminf((float)HH, yi + radius + 1.0f);
            const float sigma = fmaxf(radius * 0.5f, 1.0f);
            neg_inv = -1.0f / (2.0f * sigma * sigma);
        }
        sq0[g] = make_float4(u, v, x0, x1);
        sq1[g] = make_float4(y0, y1, neg_inv, op);
        sq2[g] = make_float4(c0, c1, c2, d);
    }
    __syncthreads();

    // ---- Phase 1: compact gaussians touching row y (ascending orig index) ----
    // wave w tests gaussians [w*64, w*64+64): exactly one ballot per wave.
    const int wave = t >> 6;
    const int lane = t & 63;
    const float4 qa = sq1[t];
    const bool fa = (yy >= qa.x) && (yy < qa.y);
    const unsigned long long ba = __ballot(fa);
    if (lane == 0) swave[wave] = __popcll(ba);
    __syncthreads();
    int base = 0;
    #pragma unroll
    for (int w = 0; w < 8; ++w) base += (w < wave) ? swave[w] : 0;
    if (t == 0) {
        sM = swave[0] + swave[1] + swave[2] + swave[3]
           + swave[4] + swave[5] + swave[6] + swave[7];
    }
    if (fa) slist[base + __popcll(ba & ((1ull << lane) - 1ull))] = t;
    __syncthreads();
    const int M = sM;

    // ---- Phase 2: sort the selected list back-to-front ----
    // key: depth desc, original index asc (== stable argsort(-depths)).
    if (t < M) {
        const int gi = slist[t];
        const float di = sq2[gi].w;
        int r = 0;
        for (int j = 0; j < M; ++j) {
            const int gj = slist[j];
            const float dj = sq2[gj].w;
            r += (dj > di) | ((dj == di) & (gj < gi));
        }
        ssort[r] = gi;
    }
    __syncthreads();

    // ---- Phase 3: per-pixel ordered blend (threads 0..255 = pixels) ----
    if (t < WW) {
        const float xx = (float)t;
        float cr = bg0;
        float cg = bg1;
        float cb = bg2;

        for (int i = 0; i < M; ++i) {
            const int gi = ssort[i];        // uniform -> broadcast reads
            const float4 q0 = sq0[gi];
            float a = 0.0f;
            if (xx >= q0.z && xx < q0.w) {
                const float4 q1 = sq1[gi];
                const float dx = xx - q0.x;
                const float dy = yy - q0.y;
                a = __expf((dx * dx + dy * dy) * q1.z) * q1.w;
                a = fminf(fmaxf(a, 0.0f), 1.0f);
            }
            const float4 q2 = sq2[gi];
            const float one_m = 1.0f - a;
            cr = a * q2.x + one_m * cr;
            cg = a * q2.y + one_m * cg;
            cb = a * q2.z + one_m * cb;
        }

        const int pix = y * WW + t;
        out[0 * HH * WW + pix] = cr;
        out[1 * HH * WW + pix] = cg;
        out[2 * HH * WW + pix] = cb;
    }
}

extern "C" void kernel_launch(void* const* d_in, const int* in_sizes, int n_in,
                              void* d_out, int out_size, void* d_ws, size_t ws_size,
                              hipStream_t stream) {
    const float* positions  = (const float*)d_in[0];
    const float* scales     = (const float*)d_in[1];
    // d_in[2] = rotations (unused by reference)
    const float* colors     = (const float*)d_in[3];
    const float* opacities  = (const float*)d_in[4];
    const float* view_matrix= (const float*)d_in[5];
    const float* background = (const float*)d_in[6];

    fused_kernel<<<HH, 2 * WW, 0, stream>>>(positions, scales, colors, opacities,
                                            view_matrix, background, (float*)d_out);
}